// Round 1
// baseline (763.264 us; speedup 1.0000x reference)
//
#include <hip/hip_runtime.h>
#include <hip/hip_bf16.h>

// ArcFace fused: normalize -> bf16 GEMM (MFMA) -> margin fixup.
// M=4096 (B), N=20000 (C), K=512 (D). Outputs: cos [B,C], logits [B,C] fp32.
//
// Key identity: for non-label columns margin terms are 0 and
// cos(arccos(x)) == x, so logits = 30*cos everywhere except (i, label[i]).

#define NB 4096
#define NC 20000
#define ND 512

typedef __bf16 bf16x8_t __attribute__((ext_vector_type(8)));
typedef float f32x4 __attribute__((ext_vector_type(4)));

__device__ __forceinline__ void gload16(const void* g, void* l) {
    // async global->LDS, 16B per lane; LDS dest is wave-uniform base + lane*16
    __builtin_amdgcn_global_load_lds(
        (__attribute__((address_space(1))) void*)(g),
        (__attribute__((address_space(3))) void*)(l),
        16, 0, 0);
}

// ---------------------------------------------------------------------------
// Pre-pass: L2-normalize rows (fp32) and cast to bf16. One wave per row.
// ---------------------------------------------------------------------------
__global__ void normalize_rows(const float* __restrict__ in,
                               unsigned short* __restrict__ out, int rows) {
    const int gw = (int)((blockIdx.x * blockDim.x + threadIdx.x) >> 6);
    const int lane = threadIdx.x & 63;
    if (gw >= rows) return;
    const float* rp = in + (size_t)gw * ND + lane * 8;
    float4 v0 = *(const float4*)rp;
    float4 v1 = *(const float4*)(rp + 4);
    float s = v0.x * v0.x + v0.y * v0.y + v0.z * v0.z + v0.w * v0.w +
              v1.x * v1.x + v1.y * v1.y + v1.z * v1.z + v1.w * v1.w;
#pragma unroll
    for (int off = 32; off; off >>= 1) s += __shfl_xor(s, off);
    const float sc = 1.0f / sqrtf(s);
    bf16x8_t o;
    o[0] = (__bf16)(v0.x * sc); o[1] = (__bf16)(v0.y * sc);
    o[2] = (__bf16)(v0.z * sc); o[3] = (__bf16)(v0.w * sc);
    o[4] = (__bf16)(v1.x * sc); o[5] = (__bf16)(v1.y * sc);
    o[6] = (__bf16)(v1.z * sc); o[7] = (__bf16)(v1.w * sc);
    *(bf16x8_t*)(out + (size_t)gw * ND + lane * 8) = o;
}

// ---------------------------------------------------------------------------
// bf16 NT GEMM, m97 structure: 128x128 tile, BK=64, 4 waves (2x2 of 64x64),
// global_load_lds width=16, 16x16x32 bf16 MFMA, dual epilogue (cos, 30*cos).
// ---------------------------------------------------------------------------
__global__ __launch_bounds__(256) void arc_gemm(
    const unsigned short* __restrict__ A,   // nf bf16 [4096][512]
    const unsigned short* __restrict__ Bw,  // nw bf16 [20000][512]
    float* __restrict__ out0, float* __restrict__ out1) {
    __shared__ unsigned short As[128 * 64];  // [row][k], 16 KiB
    __shared__ unsigned short Bs[128 * 64];  // [col][k], 16 KiB

    const int tid = threadIdx.x;
    const int lane = tid & 63;
    const int w = tid >> 6;          // wave 0..3
    const int wr = w >> 1;           // wave row (2)
    const int wc = w & 1;            // wave col (2)
    const int m0 = blockIdx.y * 128;
    const int n0 = blockIdx.x * 128;

    // staging geometry: each 1KiB LDS chunk = 8 rows of [64] bf16
    const int srow = lane >> 3;         // row within chunk
    const int scol = (lane & 7) * 8;    // k element offset (16B granule)

    f32x4 acc[4][4];
#pragma unroll
    for (int m = 0; m < 4; ++m)
#pragma unroll
        for (int n = 0; n < 4; ++n) acc[m][n] = (f32x4){0.f, 0.f, 0.f, 0.f};

    const int frow = lane & 15;          // fragment row/col within 16
    const int fko = (lane >> 4) * 8;     // fragment k base

    for (int kt = 0; kt < 8; ++kt) {     // K = 8 * 64
        const int k0 = kt * 64;
        if (kt) __syncthreads();         // protect LDS from overwrite
#pragma unroll
        for (int it = 0; it < 4; ++it) {
            const int chunk = w * 4 + it;            // 0..15, wave-uniform
            const int arow = m0 + chunk * 8 + srow;  // < 4096 always
            gload16(A + (size_t)arow * ND + k0 + scol, As + chunk * 512);
            int brow = n0 + chunk * 8 + srow;
            if (brow > NC - 1) brow = NC - 1;        // clamp ragged N edge
            gload16(Bw + (size_t)brow * ND + k0 + scol, Bs + chunk * 512);
        }
        __syncthreads();  // compiler drains vmcnt(0) before s_barrier

#pragma unroll
        for (int ks = 0; ks < 2; ++ks) {
            bf16x8_t af[4], bf[4];
            const int ko = ks * 32 + fko;
#pragma unroll
            for (int m = 0; m < 4; ++m)
                af[m] = *(const bf16x8_t*)&As[(wr * 64 + m * 16 + frow) * 64 + ko];
#pragma unroll
            for (int n = 0; n < 4; ++n)
                bf[n] = *(const bf16x8_t*)&Bs[(wc * 64 + n * 16 + frow) * 64 + ko];
#pragma unroll
            for (int m = 0; m < 4; ++m)
#pragma unroll
                for (int n = 0; n < 4; ++n)
                    acc[m][n] = __builtin_amdgcn_mfma_f32_16x16x32_bf16(
                        af[m], bf[n], acc[m][n], 0, 0, 0);
        }
    }

    // Epilogue: C/D layout col=lane&15, row=(lane>>4)*4+j  [m89-verified]
    const int cg = (lane >> 4) * 4;
#pragma unroll
    for (int m = 0; m < 4; ++m) {
#pragma unroll
        for (int n = 0; n < 4; ++n) {
            const int col = n0 + wc * 64 + n * 16 + frow;
            if (col < NC) {
                const int row = m0 + wr * 64 + m * 16 + cg;
                size_t base = (size_t)row * NC + col;
#pragma unroll
                for (int j = 0; j < 4; ++j) {
                    float v = acc[m][n][j];
                    out0[base + (size_t)j * NC] = v;
                    out1[base + (size_t)j * NC] = 30.0f * v;
                }
            }
        }
    }
}

// ---------------------------------------------------------------------------
// Fixup: logits[i, label[i]] with ArcFace margin, closed-form (no arccos):
// cos(arccos(c)+m) = c*cos(m) - sqrt(1-c^2)*sin(m)
// ---------------------------------------------------------------------------
__global__ void fixup(const int* __restrict__ label,
                      const float* __restrict__ cosO,
                      float* __restrict__ logits) {
    const int i = blockIdx.x * blockDim.x + threadIdx.x;
    if (i >= NB) return;
    const int j = label[i];
    const float c = cosO[(size_t)i * NC + j];
    const float COS_M = 0.8775825618903728f;   // cos(0.5)
    const float SIN_M = 0.4794255386042030f;   // sin(0.5)
    float v;
    if (c > -COS_M) {  // hit: apply angular margin
        float sn = sqrtf(fmaxf(0.f, 1.f - c * c));
        v = 30.0f * (c * COS_M - sn * SIN_M);
    } else {           // miss: linear extension
        v = 30.0f * (c - 0.2397127693021015f);  // c + (-0.5*sin(0.5))
    }
    logits[(size_t)i * NC + j] = v;
}

extern "C" void kernel_launch(void* const* d_in, const int* in_sizes, int n_in,
                              void* d_out, int out_size, void* d_ws, size_t ws_size,
                              hipStream_t stream) {
    const float* feat = (const float*)d_in[0];
    const int* label = (const int*)d_in[1];
    const float* wts = (const float*)d_in[2];
    float* out0 = (float*)d_out;                       // cos [4096,20000]
    float* out1 = out0 + (size_t)NB * NC;              // logits [4096,20000]
    unsigned short* nf = (unsigned short*)d_ws;        // 4096*512 bf16 = 4 MB
    unsigned short* nw = nf + (size_t)NB * ND;         // 20000*512 bf16 = 20.5 MB

    normalize_rows<<<NB / 4, 256, 0, stream>>>(feat, nf, NB);
    normalize_rows<<<NC / 4, 256, 0, stream>>>(wts, nw, NC);
    arc_gemm<<<dim3((NC + 127) / 128, NB / 128), 256, 0, stream>>>(nf, nw, out0, out1);
    fixup<<<(NB + 255) / 256, 256, 0, stream>>>(label, out0, out1);
}